// Round 12
// baseline (117.719 us; speedup 1.0000x reference)
//
#include <hip/hip_runtime.h>

// XConv bf16-MFMA pipeline, fragment-packed weights + packed dw handoff.
// kB: 2 waves per point, split by c-range, barrier-free.
// N=16, P=1024, K=16, D=3, Cf=64, Fin=64, Ccat=128, DM=4, Cout=128.
//
// MFMA conventions (mfma_f32_16x16x32_bf16, m89-verified):
//  A-frag: lane&15 = M-row, k = (lane>>4)*8 + [0..7]  ([M][K] row-major)
//  B-frag: lane&15 = N-col, k = (lane>>4)*8 + [0..7]  ([N][K] row-major)
//  D:      col(N) = lane&15, row(M) = (lane>>4)*4 + reg
//
// Packed weight layout (per [O][K] weight, 16-col tiles, K-steps of 32):
//  Wpk[((ot*(K/32) + ks)*64 + lane)*8 + e] = W[ot*16 + (lane&15)][ks*32 + (lane>>4)*8 + e]
// Packed dw handoff (A-frag order for kC):
//  dwPk[(((p>>4)*16 + (k>>5))*64 + ((k>>3)&3)*16 + (p&15))*8 + (k&7)] = dw[p][k]

#define NPTS 16384

typedef short  s16x8 __attribute__((ext_vector_type(8)));
typedef float  f32x4 __attribute__((ext_vector_type(4)));

__device__ inline unsigned short f2b(float f) {
    unsigned u = __builtin_bit_cast(unsigned, f);
    unsigned r = u + 0x7FFF + ((u >> 16) & 1);
    return (unsigned short)(r >> 16);
}
__device__ inline float b2f(unsigned short b) {
    return __builtin_bit_cast(float, (unsigned)b << 16);
}
// packed RNE f32x2 -> bf16x2 (lo -> [15:0], hi -> [31:16])
__device__ inline unsigned cvtpk(float lo, float hi) {
    unsigned r;
    asm("v_cvt_pk_bf16_f32 %0, %1, %2" : "=v"(r) : "v"(lo), "v"(hi));
    return r;
}

#define MFMA(a,b,c) __builtin_amdgcn_mfma_f32_16x16x32_bf16((a),(b),(c),0,0,0)

// ---------------- kW: weight prep (frag-packed) + W1 pack + Wt + acc zero ----------------
__global__ __launch_bounds__(256) void kW_cvt(
    const float* __restrict__ Wxc, const float* __restrict__ Wx1,
    const float* __restrict__ Wx2, const float* __restrict__ Wf2,
    const float* __restrict__ Wpw, const float* __restrict__ Wf1,
    const float* __restrict__ bf1, const float* __restrict__ Wdw,
    unsigned short* __restrict__ Wpk, float* __restrict__ W1p,
    unsigned short* __restrict__ Wtb, float* __restrict__ acc)
{
    unsigned short* Wxcpk = Wpk;             // O=256 K=64   : 16384
    unsigned short* Wx1pk = Wpk + 16384;     // O=256 K=256  : 65536
    unsigned short* Wx2pk = Wpk + 81920;     // O=256 K=256  : 65536
    unsigned short* Wf2pk = Wpk + 147456;    // O=64  K=64   : 4096
    unsigned short* Wpwpk = Wpk + 151552;    // O=128 K=512  : 65536
    int idx = blockIdx.x * 256 + threadIdx.x;
    if (idx < 16384) {            // Wxc [256][48] -> K=64 pad
        int e = idx & 7, ln = (idx >> 3) & 63, ks = (idx >> 9) & 1, ot = idx >> 10;
        int row = ot*16 + (ln & 15), k = ks*32 + (ln >> 4)*8 + e;
        Wxcpk[idx] = (k < 48) ? f2b(Wxc[row*48 + k]) : 0; return; }
    idx -= 16384;
    if (idx < 65536) {            // Wx1 [256][256]
        int e = idx & 7, ln = (idx >> 3) & 63, ks = (idx >> 9) & 7, ot = idx >> 12;
        int row = ot*16 + (ln & 15), k = ks*32 + (ln >> 4)*8 + e;
        Wx1pk[idx] = f2b(Wx1[row*256 + k]); return; }
    idx -= 65536;
    if (idx < 65536) {            // Wx2 [256][256]
        int e = idx & 7, ln = (idx >> 3) & 63, ks = (idx >> 9) & 7, ot = idx >> 12;
        int row = ot*16 + (ln & 15), k = ks*32 + (ln >> 4)*8 + e;
        Wx2pk[idx] = f2b(Wx2[row*256 + k]); return; }
    idx -= 65536;
    if (idx < 4096) {             // Wf2 [64][64]
        int e = idx & 7, ln = (idx >> 3) & 63, ks = (idx >> 9) & 1, ot = idx >> 10;
        int row = ot*16 + (ln & 15), k = ks*32 + (ln >> 4)*8 + e;
        Wf2pk[idx] = f2b(Wf2[row*64 + k]); return; }
    idx -= 4096;
    if (idx < 65536) {            // Wpw [128][512]
        int e = idx & 7, ln = (idx >> 3) & 63, ks = (idx >> 9) & 15, ot = idx >> 13;
        int row = ot*16 + (ln & 15), k = ks*32 + (ln >> 4)*8 + e;
        Wpwpk[idx] = f2b(Wpw[row*512 + k]); return; }
    idx -= 65536;
    if (idx < 256)   { int f = idx >> 2, j = idx & 3;
        W1p[idx] = (j < 3) ? Wf1[f*3 + j] : bf1[f]; return; }
    idx -= 256;
    if (idx < 8192)  { int m = idx >> 11, rem = idx & 2047;   // Wtb[m][c][k]
        int c = rem >> 4, k = rem & 15;
        Wtb[idx] = f2b(Wdw[(size_t)(c*4 + m)*16 + k]); return; }
    idx -= 8192;
    if (idx < 256)   { acc[idx] = 0.f; return; }              // accS|accS2
}

// ---------------- kA v3: X-chain, 32 pts/block, 512 thr, cvt_pk epilogues ----------------
#define SX 264
__global__ __launch_bounds__(512) void kA_mfma(
    const float* __restrict__ rep, const float* __restrict__ pts,
    const unsigned short* __restrict__ Wpk,
    const float* __restrict__ bxc, const float* __restrict__ bx1,
    const float* __restrict__ bx2, unsigned short* __restrict__ X3b)
{
    const unsigned short* Wxcpk = Wpk;
    const unsigned short* Wx1pk = Wpk + 16384;
    const unsigned short* Wx2pk = Wpk + 81920;
    __shared__ __align__(16) unsigned short X1s[32*SX];
    __shared__ __align__(16) unsigned short X2s[32*SX];
    const int tid = threadIdx.x;
    const int w = tid >> 6, lane = tid & 63, cl = lane & 15, lg = lane >> 4;
    const int mw = w & 1, nw = w >> 1;
    const int base = blockIdx.x * 32;
    const int q = base + mw*16 + cl;
    f32x4 z = {0.f,0.f,0.f,0.f};

    // ---- ph1 A-frag from global, packed conversions ----
    float r0 = rep[q*3+0], r1 = rep[q*3+1], r2 = rep[q*3+2];
    s16x8 aa[2];
    #pragma unroll
    for (int ks = 0; ks < 2; ++ks) {
        uint4 au;
        #pragma unroll
        for (int e2 = 0; e2 < 4; ++e2) {
            float v[2];
            #pragma unroll
            for (int h = 0; h < 2; ++h) {
                int j = ks*32 + lg*8 + e2*2 + h;
                float vv = 0.f;
                if (j < 48) {
                    int d = j >> 4, kk = j & 15;
                    float rv = (d == 0) ? r0 : ((d == 1) ? r1 : r2);
                    vv = pts[(size_t)(q*16 + kk)*3 + d] - rv;
                }
                v[h] = vv;
            }
            ((unsigned*)&au)[e2] = cvtpk(v[0], v[1]);
        }
        aa[ks] = __builtin_bit_cast(s16x8, au);
    }

    {   // ph1: X1 = relu(ptsl @ Wxc^T + b), K=64
        f32x4 acc[4] = {z,z,z,z};
        #pragma unroll
        for (int ks = 0; ks < 2; ++ks) {
            #pragma unroll
            for (int ct = 0; ct < 4; ++ct) {
                int ot = nw*4 + ct;
                s16x8 b = *(const s16x8*)&Wxcpk[((ot*2 + ks)*64 + lane)*8];
                acc[ct] = MFMA(aa[ks], b, acc[ct]);
            }
        }
        #pragma unroll
        for (int ct = 0; ct < 4; ++ct) {
            int o = nw*64 + ct*16 + cl;
            float bias = bxc[o];
            int rb = (mw*16 + lg*4)*SX + o;
            unsigned u0 = cvtpk(fmaxf(acc[ct][0]+bias,0.f), fmaxf(acc[ct][1]+bias,0.f));
            unsigned u1 = cvtpk(fmaxf(acc[ct][2]+bias,0.f), fmaxf(acc[ct][3]+bias,0.f));
            X1s[rb       ] = (unsigned short)u0;
            X1s[rb +   SX] = (unsigned short)(u0 >> 16);
            X1s[rb + 2*SX] = (unsigned short)u1;
            X1s[rb + 3*SX] = (unsigned short)(u1 >> 16);
        }
    }
    __syncthreads();

    {   // ph2: X2 = relu(X1 @ Wx1^T + b), K=256
        f32x4 acc[4] = {z,z,z,z};
        #pragma unroll
        for (int ks = 0; ks < 8; ++ks) {
            s16x8 a = *(const s16x8*)&X1s[(mw*16 + cl)*SX + ks*32 + lg*8];
            #pragma unroll
            for (int ct = 0; ct < 4; ++ct) {
                int ot = nw*4 + ct;
                s16x8 b = *(const s16x8*)&Wx1pk[((ot*8 + ks)*64 + lane)*8];
                acc[ct] = MFMA(a, b, acc[ct]);
            }
        }
        #pragma unroll
        for (int ct = 0; ct < 4; ++ct) {
            int o = nw*64 + ct*16 + cl;
            float bias = bx1[o];
            int rb = (mw*16 + lg*4)*SX + o;
            unsigned u0 = cvtpk(fmaxf(acc[ct][0]+bias,0.f), fmaxf(acc[ct][1]+bias,0.f));
            unsigned u1 = cvtpk(fmaxf(acc[ct][2]+bias,0.f), fmaxf(acc[ct][3]+bias,0.f));
            X2s[rb       ] = (unsigned short)u0;
            X2s[rb +   SX] = (unsigned short)(u0 >> 16);
            X2s[rb + 2*SX] = (unsigned short)u1;
            X2s[rb + 3*SX] = (unsigned short)(u1 >> 16);
        }
    }
    __syncthreads();

    {   // ph3: X3 = X2 @ Wx2^T + b (linear) -> global bf16 [p][256]
        f32x4 acc[4] = {z,z,z,z};
        #pragma unroll
        for (int ks = 0; ks < 8; ++ks) {
            s16x8 a = *(const s16x8*)&X2s[(mw*16 + cl)*SX + ks*32 + lg*8];
            #pragma unroll
            for (int ct = 0; ct < 4; ++ct) {
                int ot = nw*4 + ct;
                s16x8 b = *(const s16x8*)&Wx2pk[((ot*8 + ks)*64 + lane)*8];
                acc[ct] = MFMA(a, b, acc[ct]);
            }
        }
        #pragma unroll
        for (int ct = 0; ct < 4; ++ct) {
            int o = nw*64 + ct*16 + cl;
            float bias = bx2[o];
            size_t rb = (size_t)(base + mw*16 + lg*4)*256 + o;
            unsigned u0 = cvtpk(acc[ct][0]+bias, acc[ct][1]+bias);
            unsigned u1 = cvtpk(acc[ct][2]+bias, acc[ct][3]+bias);
            X3b[rb      ] = (unsigned short)u0;
            X3b[rb + 256] = (unsigned short)(u0 >> 16);
            X3b[rb + 512] = (unsigned short)u1;
            X3b[rb + 768] = (unsigned short)(u1 >> 16);
        }
    }
}

// ---------------- kB v9: 2 waves/point, c-range split, barrier-free ----------------
// 512 thr = 8 waves, 4 points/block. Wave (u,hf): point p = blk*4+u.
//  hf=0: FC1+FC2 -> fcT[c<64][rw..], then ct 0..3 (reads only c<64 = own writes)
//  hf=1: fts stage -> fcT[c>=64][rw..], then ct 4..7 (own writes)
// No __syncthreads: every wave reads only LDS it wrote (in-order DS pipe).
#define SF 72
__global__ __launch_bounds__(512) void kB_mfma(
    const float* __restrict__ rep, const float* __restrict__ pts,
    const float* __restrict__ fts, const float* __restrict__ W1p,
    const unsigned short* __restrict__ Wpk, const float* __restrict__ bf2,
    const unsigned short* __restrict__ Wtb, const float* __restrict__ bdw,
    const unsigned short* __restrict__ X3b, unsigned short* __restrict__ dwPk)
{
    const unsigned short* Wf2pk = Wpk + 147456;
    __shared__ __align__(16) unsigned short fcT[128*SF];  // [c][row0..63], 18432 B
    const int tid = threadIdx.x;
    const int w = tid >> 6, lane = tid & 63, cl = lane & 15, lg = lane >> 4;
    const int u = w >> 1, hf = w & 1;
    const int p = blockIdx.x*4 + u;
    const int rw = u*16;

    // X A-frag (K 16->32 zero-pad) — both halves need it; issue first
    s16x8 xa = {0,0,0,0,0,0,0,0};
    if (lg < 2) xa = *(const s16x8*)&X3b[(size_t)p*256 + cl*16 + lg*8];

    f32x4 z = {0.f,0.f,0.f,0.f};

    if (hf == 0) {
        // ---- lift half: FC1 (regs) + FC2 (swapped MFMA) -> fcT[c<64] ----
        const int row = p*16 + cl;
        float x0 = pts[(size_t)row*3+0] - rep[p*3+0];
        float x1 = pts[(size_t)row*3+1] - rep[p*3+1];
        float x2 = pts[(size_t)row*3+2] - rep[p*3+2];
        s16x8 hb[2];
        #pragma unroll
        for (int ks = 0; ks < 2; ++ks) {
            uint4 hu;
            #pragma unroll
            for (int e2 = 0; e2 < 4; ++e2) {
                int f0 = ks*32 + lg*8 + e2*2;
                float4 wa = *(const float4*)&W1p[f0*4];
                float4 wb = *(const float4*)&W1p[(f0+1)*4];
                float h0 = fmaxf(wa.w + wa.x*x0 + wa.y*x1 + wa.z*x2, 0.f);
                float h1 = fmaxf(wb.w + wb.x*x0 + wb.y*x1 + wb.z*x2, 0.f);
                ((unsigned*)&hu)[e2] = cvtpk(h0, h1);
            }
            hb[ks] = __builtin_bit_cast(s16x8, hu);
        }
        f32x4 acc2[4] = {z,z,z,z};
        #pragma unroll
        for (int ks = 0; ks < 2; ++ks) {
            #pragma unroll
            for (int gt = 0; gt < 4; ++gt) {
                s16x8 a = *(const s16x8*)&Wf2pk[((gt*2 + ks)*64 + lane)*8];
                acc2[gt] = MFMA(a, hb[ks], acc2[gt]);
            }
        }
        #pragma unroll
        for (int gt = 0; gt < 4; ++gt) {
            int g0 = gt*16 + lg*4;
            unsigned u0 = cvtpk(fmaxf(acc2[gt][0]+bf2[g0+0],0.f),
                                fmaxf(acc2[gt][1]+bf2[g0+1],0.f));
            unsigned u1 = cvtpk(fmaxf(acc2[gt][2]+bf2[g0+2],0.f),
                                fmaxf(acc2[gt][3]+bf2[g0+3],0.f));
            int rb = g0*SF + rw + cl;
            fcT[rb       ] = (unsigned short)u0;
            fcT[rb +   SF] = (unsigned short)(u0 >> 16);
            fcT[rb + 2*SF] = (unsigned short)u1;
            fcT[rb + 3*SF] = (unsigned short)(u1 >> 16);
        }
    } else {
        // ---- fts half: transposed stage -> fcT[c>=64] ----
        const int frow = lane >> 2, fch = lane & 3;
        float4 fv[4];
        #pragma unroll
        for (int it = 0; it < 4; ++it)
            fv[it] = *(const float4*)&fts[((size_t)p*16 + frow)*64 + fch*4 + it*16];
        #pragma unroll
        for (int it = 0; it < 4; ++it) {
            int c0 = fch*4 + it*16;
            unsigned u0 = cvtpk(fv[it].x, fv[it].y);
            unsigned u1 = cvtpk(fv[it].z, fv[it].w);
            int rb = (64 + c0)*SF + rw + frow;
            fcT[rb       ] = (unsigned short)u0;
            fcT[rb +   SF] = (unsigned short)(u0 >> 16);
            fcT[rb + 2*SF] = (unsigned short)u1;
            fcT[rb + 3*SF] = (unsigned short)(u1 >> 16);
        }
    }

    // ---- own-half fts_X + depthwise (reads only this wave's fcT region) ----
    const int ctb = hf*4;
    #pragma unroll
    for (int ci = 0; ci < 4; ++ci) {
        int ct = ctb + ci;
        int c = ct*16 + cl;
        s16x8 b = *(const s16x8*)&fcT[c*SF + rw + (lg & 1)*8];
        f32x4 fx = MFMA(xa, b, z);

        float4 b4 = *(const float4*)&bdw[c*4];
        float om[4];
        #pragma unroll
        for (int m = 0; m < 4; ++m) {
            ushort4 wu = *(const ushort4*)&Wtb[m*2048 + c*16 + lg*4];
            float s = fx[0]*b2f(wu.x) + fx[1]*b2f(wu.y)
                    + fx[2]*b2f(wu.z) + fx[3]*b2f(wu.w);
            s += __shfl_xor(s, 16);
            s += __shfl_xor(s, 32);
            om[m] = s + ((const float*)&b4)[m];
        }
        if (lg == 0) {
            unsigned u0 = cvtpk(om[0], om[1]);
            unsigned u1 = cvtpk(om[2], om[3]);
            uint2 pk; pk.x = u0; pk.y = u1;
            size_t a = ((((size_t)(p >> 4)*16 + ct*2 + (cl >> 3))*64
                        + ((cl >> 1) & 3)*16 + (p & 15))*8 + (cl & 1)*4);
            *(uint2*)&dwPk[a] = pk;
        }
    }
}

// ---------------- kC: pointwise MFMA GEMM (packed A) + BN stats, y bf16 ----------------
__global__ __launch_bounds__(256) void kC_mfma(
    const unsigned short* __restrict__ dwPk, const unsigned short* __restrict__ Wpk,
    const float* __restrict__ bpw, unsigned short* __restrict__ yb,
    float* __restrict__ accS, float* __restrict__ accS2)
{
    const unsigned short* Wpwpk = Wpk + 151552;
    const int tid = threadIdx.x;
    const int w = tid >> 6, lane = tid & 63, cl = lane & 15, lg = lane >> 4;
    const int mt = blockIdx.x*2 + (w & 1);     // 16-point m-tile
    const int m0 = mt*16;
    const int nh = w >> 1;
    f32x4 z = {0.f,0.f,0.f,0.f};
    f32x4 acc[4] = {z,z,z,z};
    for (int ks = 0; ks < 16; ++ks) {
        s16x8 a = *(const s16x8*)&dwPk[(((size_t)mt*16 + ks)*64 + lane)*8];
        #pragma unroll
        for (int ct = 0; ct < 4; ++ct) {
            int ot = nh*4 + ct;
            s16x8 b = *(const s16x8*)&Wpwpk[((ot*16 + ks)*64 + lane)*8];
            acc[ct] = MFMA(a, b, acc[ct]);
        }
    }
    #pragma unroll
    for (int ct = 0; ct < 4; ++ct) {
        int o = nh*64 + ct*16 + cl;
        float bias = bpw[o];
        float s1 = 0.f, s2 = 0.f;
        #pragma unroll
        for (int r = 0; r < 4; ++r) {
            float v = acc[ct][r] + bias;
            yb[(size_t)(m0 + lg*4 + r)*128 + o] = f2b(v);
            s1 += v; s2 += v*v;
        }
        s1 += __shfl_xor(s1, 16); s2 += __shfl_xor(s2, 16);
        s1 += __shfl_xor(s1, 32); s2 += __shfl_xor(s2, 32);
        if (lg == 0) {
            atomicAdd(accS + o, s1);
            atomicAdd(accS2 + o, s2);
        }
    }
}

// ---------------- kE: BN finalize (inline) + normalize + relu, bf16 y in ----------------
__global__ __launch_bounds__(256) void kE_final(
    const unsigned short* __restrict__ yb, const float* __restrict__ accS,
    const float* __restrict__ accS2, const float* __restrict__ gamma,
    const float* __restrict__ beta, float* __restrict__ out)
{
    __shared__ float stl[256];
    const int tid = threadIdx.x;
    if (tid < 128) {
        float mean = accS[tid] * (1.f/NPTS);
        float var  = accS2[tid] * (1.f/NPTS) - mean*mean;
        float rstd = rsqrtf(var + 1e-5f);
        float sc = gamma[tid] * rstd;
        stl[tid] = sc;
        stl[128 + tid] = beta[tid] - mean*sc;
    }
    __syncthreads();
    const int idx = blockIdx.x*256 + tid;
    ushort4 u = *(const ushort4*)&yb[(size_t)idx*4];
    int o0 = (idx & 31) << 2;
    float4 sc = *(const float4*)&stl[o0];
    float4 sh = *(const float4*)&stl[128 + o0];
    float4 r;
    r.x = fmaxf(b2f(u.x)*sc.x + sh.x, 0.f);
    r.y = fmaxf(b2f(u.y)*sc.y + sh.y, 0.f);
    r.z = fmaxf(b2f(u.z)*sc.z + sh.z, 0.f);
    r.w = fmaxf(b2f(u.w)*sc.w + sh.w, 0.f);
    ((float4*)out)[idx] = r;
}

extern "C" void kernel_launch(void* const* d_in, const int* in_sizes, int n_in,
                              void* d_out, int out_size, void* d_ws, size_t ws_size,
                              hipStream_t stream) {
    const float* rep  = (const float*)d_in[0];
    const float* pts  = (const float*)d_in[1];
    const float* fts  = (const float*)d_in[2];
    const float* Wf1  = (const float*)d_in[3];
    const float* bf1  = (const float*)d_in[4];
    const float* Wf2  = (const float*)d_in[5];
    const float* bf2  = (const float*)d_in[6];
    const float* Wxc  = (const float*)d_in[7];
    const float* bxc  = (const float*)d_in[8];
    const float* Wx1  = (const float*)d_in[9];
    const float* bx1  = (const float*)d_in[10];
    const float* Wx2  = (const float*)d_in[11];
    const float* bx2  = (const float*)d_in[12];
    const float* Wdw  = (const float*)d_in[13];
    const float* bdw  = (const float*)d_in[14];
    const float* Wpw  = (const float*)d_in[15];
    const float* bpw  = (const float*)d_in[16];
    const float* gam  = (const float*)d_in[17];
    const float* bet  = (const float*)d_in[18];

    unsigned short* X3b  = (unsigned short*)d_ws;                // 16384*256 bf16
    unsigned short* dwPk = X3b + (size_t)NPTS*256;               // 16384*512 bf16
    unsigned short* yb   = dwPk + (size_t)NPTS*512;              // 16384*128 bf16
    float* acc = (float*)(yb + (size_t)NPTS*128);                // 256 (accS|accS2)
    unsigned short* Wpk = (unsigned short*)(acc + 256);          // 217088 bf16
    float* W1p = (float*)(Wpk + 217088);                         // 256 f32
    unsigned short* Wtb = (unsigned short*)(W1p + 256);          // 8192 bf16

    kW_cvt<<<882, 256, 0, stream>>>(Wxc, Wx1, Wx2, Wf2, Wpw, Wf1, bf1, Wdw,
                                    Wpk, W1p, Wtb, acc);
    kA_mfma<<<NPTS/32, 512, 0, stream>>>(rep, pts, Wpk, bxc, bx1, bx2, X3b);
    kB_mfma<<<NPTS/4, 512, 0, stream>>>(rep, pts, fts, W1p, Wpk, bf2, Wtb, bdw, X3b, dwPk);
    kC_mfma<<<NPTS/32, 256, 0, stream>>>(dwPk, Wpk, bpw, yb, acc, acc + 128);
    kE_final<<<(NPTS*128/4)/256, 256, 0, stream>>>(yb, acc, acc + 128, gam, bet, (float*)d_out);
}

// Round 13
// 108.420 us; speedup vs baseline: 1.0858x; 1.0858x over previous
//
#include <hip/hip_runtime.h>

// XConv bf16-MFMA pipeline, fragment-packed weights + packed dw handoff.
// kA: B-fragment reuse (wave = N-eighth, loops both m-tiles).
// kB: 2 waves per point, split by c-range, barrier-free.
// N=16, P=1024, K=16, D=3, Cf=64, Fin=64, Ccat=128, DM=4, Cout=128.
//
// MFMA conventions (mfma_f32_16x16x32_bf16, m89-verified):
//  A-frag: lane&15 = M-row, k = (lane>>4)*8 + [0..7]  ([M][K] row-major)
//  B-frag: lane&15 = N-col, k = (lane>>4)*8 + [0..7]  ([N][K] row-major)
//  D:      col(N) = lane&15, row(M) = (lane>>4)*4 + reg
//
// Packed weight layout (per [O][K] weight, 16-col tiles, K-steps of 32):
//  Wpk[((ot*(K/32) + ks)*64 + lane)*8 + e] = W[ot*16 + (lane&15)][ks*32 + (lane>>4)*8 + e]
// Packed dw handoff (A-frag order for kC):
//  dwPk[(((p>>4)*16 + (k>>5))*64 + ((k>>3)&3)*16 + (p&15))*8 + (k&7)] = dw[p][k]

#define NPTS 16384

typedef short  s16x8 __attribute__((ext_vector_type(8)));
typedef float  f32x4 __attribute__((ext_vector_type(4)));

__device__ inline unsigned short f2b(float f) {
    unsigned u = __builtin_bit_cast(unsigned, f);
    unsigned r = u + 0x7FFF + ((u >> 16) & 1);
    return (unsigned short)(r >> 16);
}
__device__ inline float b2f(unsigned short b) {
    return __builtin_bit_cast(float, (unsigned)b << 16);
}
// packed RNE f32x2 -> bf16x2 (lo -> [15:0], hi -> [31:16])
__device__ inline unsigned cvtpk(float lo, float hi) {
    unsigned r;
    asm("v_cvt_pk_bf16_f32 %0, %1, %2" : "=v"(r) : "v"(lo), "v"(hi));
    return r;
}

#define MFMA(a,b,c) __builtin_amdgcn_mfma_f32_16x16x32_bf16((a),(b),(c),0,0,0)

// ---------------- kW: weight prep (frag-packed) + W1 pack + Wt + acc zero ----------------
__global__ __launch_bounds__(256) void kW_cvt(
    const float* __restrict__ Wxc, const float* __restrict__ Wx1,
    const float* __restrict__ Wx2, const float* __restrict__ Wf2,
    const float* __restrict__ Wpw, const float* __restrict__ Wf1,
    const float* __restrict__ bf1, const float* __restrict__ Wdw,
    unsigned short* __restrict__ Wpk, float* __restrict__ W1p,
    unsigned short* __restrict__ Wtb, float* __restrict__ acc)
{
    unsigned short* Wxcpk = Wpk;             // O=256 K=64   : 16384
    unsigned short* Wx1pk = Wpk + 16384;     // O=256 K=256  : 65536
    unsigned short* Wx2pk = Wpk + 81920;     // O=256 K=256  : 65536
    unsigned short* Wf2pk = Wpk + 147456;    // O=64  K=64   : 4096
    unsigned short* Wpwpk = Wpk + 151552;    // O=128 K=512  : 65536
    int idx = blockIdx.x * 256 + threadIdx.x;
    if (idx < 16384) {            // Wxc [256][48] -> K=64 pad
        int e = idx & 7, ln = (idx >> 3) & 63, ks = (idx >> 9) & 1, ot = idx >> 10;
        int row = ot*16 + (ln & 15), k = ks*32 + (ln >> 4)*8 + e;
        Wxcpk[idx] = (k < 48) ? f2b(Wxc[row*48 + k]) : 0; return; }
    idx -= 16384;
    if (idx < 65536) {            // Wx1 [256][256]
        int e = idx & 7, ln = (idx >> 3) & 63, ks = (idx >> 9) & 7, ot = idx >> 12;
        int row = ot*16 + (ln & 15), k = ks*32 + (ln >> 4)*8 + e;
        Wx1pk[idx] = f2b(Wx1[row*256 + k]); return; }
    idx -= 65536;
    if (idx < 65536) {            // Wx2 [256][256]
        int e = idx & 7, ln = (idx >> 3) & 63, ks = (idx >> 9) & 7, ot = idx >> 12;
        int row = ot*16 + (ln & 15), k = ks*32 + (ln >> 4)*8 + e;
        Wx2pk[idx] = f2b(Wx2[row*256 + k]); return; }
    idx -= 65536;
    if (idx < 4096) {             // Wf2 [64][64]
        int e = idx & 7, ln = (idx >> 3) & 63, ks = (idx >> 9) & 1, ot = idx >> 10;
        int row = ot*16 + (ln & 15), k = ks*32 + (ln >> 4)*8 + e;
        Wf2pk[idx] = f2b(Wf2[row*64 + k]); return; }
    idx -= 4096;
    if (idx < 65536) {            // Wpw [128][512]
        int e = idx & 7, ln = (idx >> 3) & 63, ks = (idx >> 9) & 15, ot = idx >> 13;
        int row = ot*16 + (ln & 15), k = ks*32 + (ln >> 4)*8 + e;
        Wpwpk[idx] = f2b(Wpw[row*512 + k]); return; }
    idx -= 65536;
    if (idx < 256)   { int f = idx >> 2, j = idx & 3;
        W1p[idx] = (j < 3) ? Wf1[f*3 + j] : bf1[f]; return; }
    idx -= 256;
    if (idx < 8192)  { int m = idx >> 11, rem = idx & 2047;   // Wtb[m][c][k]
        int c = rem >> 4, k = rem & 15;
        Wtb[idx] = f2b(Wdw[(size_t)(c*4 + m)*16 + k]); return; }
    idx -= 8192;
    if (idx < 256)   { acc[idx] = 0.f; return; }              // accS|accS2
}

// ---------------- kA v4: X-chain, 32 pts/block, 512 thr, B-frag reuse ----------------
// wave w = nw eighth (2 col-tiles: ot = w*2+ct); loops mw 0..1 reusing each
// B-fragment for both m-tiles (halves L2 weight traffic, 2x MFMA per load).
#define SX 264
__global__ __launch_bounds__(512) void kA_mfma(
    const float* __restrict__ rep, const float* __restrict__ pts,
    const unsigned short* __restrict__ Wpk,
    const float* __restrict__ bxc, const float* __restrict__ bx1,
    const float* __restrict__ bx2, unsigned short* __restrict__ X3b)
{
    const unsigned short* Wxcpk = Wpk;
    const unsigned short* Wx1pk = Wpk + 16384;
    const unsigned short* Wx2pk = Wpk + 81920;
    __shared__ __align__(16) unsigned short X1s[32*SX];
    __shared__ __align__(16) unsigned short X2s[32*SX];
    const int tid = threadIdx.x;
    const int w = tid >> 6, lane = tid & 63, cl = lane & 15, lg = lane >> 4;
    const int base = blockIdx.x * 32;
    f32x4 z = {0.f,0.f,0.f,0.f};

    // ---- A-frags for both m-tiles from global, packed conversions ----
    s16x8 aa[2][2];                       // [mw][ks]
    #pragma unroll
    for (int mw = 0; mw < 2; ++mw) {
        const int q = base + mw*16 + cl;
        float r0 = rep[q*3+0], r1 = rep[q*3+1], r2 = rep[q*3+2];
        #pragma unroll
        for (int ks = 0; ks < 2; ++ks) {
            uint4 au;
            #pragma unroll
            for (int e2 = 0; e2 < 4; ++e2) {
                float v[2];
                #pragma unroll
                for (int h = 0; h < 2; ++h) {
                    int j = ks*32 + lg*8 + e2*2 + h;
                    float vv = 0.f;
                    if (j < 48) {
                        int d = j >> 4, kk = j & 15;
                        float rv = (d == 0) ? r0 : ((d == 1) ? r1 : r2);
                        vv = pts[(size_t)(q*16 + kk)*3 + d] - rv;
                    }
                    v[h] = vv;
                }
                ((unsigned*)&au)[e2] = cvtpk(v[0], v[1]);
            }
            aa[mw][ks] = __builtin_bit_cast(s16x8, au);
        }
    }

    {   // ph1: X1 = relu(ptsl @ Wxc^T + b), K=64; B reused across mw
        f32x4 acc[2][2] = {{z,z},{z,z}};  // [mw][ct]
        #pragma unroll
        for (int ks = 0; ks < 2; ++ks) {
            #pragma unroll
            for (int ct = 0; ct < 2; ++ct) {
                int ot = w*2 + ct;
                s16x8 b = *(const s16x8*)&Wxcpk[((ot*2 + ks)*64 + lane)*8];
                acc[0][ct] = MFMA(aa[0][ks], b, acc[0][ct]);
                acc[1][ct] = MFMA(aa[1][ks], b, acc[1][ct]);
            }
        }
        #pragma unroll
        for (int mw = 0; mw < 2; ++mw)
        #pragma unroll
        for (int ct = 0; ct < 2; ++ct) {
            int o = w*32 + ct*16 + cl;
            float bias = bxc[o];
            int rb = (mw*16 + lg*4)*SX + o;
            unsigned u0 = cvtpk(fmaxf(acc[mw][ct][0]+bias,0.f), fmaxf(acc[mw][ct][1]+bias,0.f));
            unsigned u1 = cvtpk(fmaxf(acc[mw][ct][2]+bias,0.f), fmaxf(acc[mw][ct][3]+bias,0.f));
            X1s[rb       ] = (unsigned short)u0;
            X1s[rb +   SX] = (unsigned short)(u0 >> 16);
            X1s[rb + 2*SX] = (unsigned short)u1;
            X1s[rb + 3*SX] = (unsigned short)(u1 >> 16);
        }
    }
    __syncthreads();

    {   // ph2: X2 = relu(X1 @ Wx1^T + b), K=256; B reused across mw
        f32x4 acc[2][2] = {{z,z},{z,z}};
        #pragma unroll
        for (int ks = 0; ks < 8; ++ks) {
            s16x8 a0 = *(const s16x8*)&X1s[(cl)*SX + ks*32 + lg*8];
            s16x8 a1 = *(const s16x8*)&X1s[(16 + cl)*SX + ks*32 + lg*8];
            #pragma unroll
            for (int ct = 0; ct < 2; ++ct) {
                int ot = w*2 + ct;
                s16x8 b = *(const s16x8*)&Wx1pk[((ot*8 + ks)*64 + lane)*8];
                acc[0][ct] = MFMA(a0, b, acc[0][ct]);
                acc[1][ct] = MFMA(a1, b, acc[1][ct]);
            }
        }
        #pragma unroll
        for (int mw = 0; mw < 2; ++mw)
        #pragma unroll
        for (int ct = 0; ct < 2; ++ct) {
            int o = w*32 + ct*16 + cl;
            float bias = bx1[o];
            int rb = (mw*16 + lg*4)*SX + o;
            unsigned u0 = cvtpk(fmaxf(acc[mw][ct][0]+bias,0.f), fmaxf(acc[mw][ct][1]+bias,0.f));
            unsigned u1 = cvtpk(fmaxf(acc[mw][ct][2]+bias,0.f), fmaxf(acc[mw][ct][3]+bias,0.f));
            X2s[rb       ] = (unsigned short)u0;
            X2s[rb +   SX] = (unsigned short)(u0 >> 16);
            X2s[rb + 2*SX] = (unsigned short)u1;
            X2s[rb + 3*SX] = (unsigned short)(u1 >> 16);
        }
    }
    __syncthreads();

    {   // ph3: X3 = X2 @ Wx2^T + b (linear) -> global bf16 [p][256]
        f32x4 acc[2][2] = {{z,z},{z,z}};
        #pragma unroll
        for (int ks = 0; ks < 8; ++ks) {
            s16x8 a0 = *(const s16x8*)&X2s[(cl)*SX + ks*32 + lg*8];
            s16x8 a1 = *(const s16x8*)&X2s[(16 + cl)*SX + ks*32 + lg*8];
            #pragma unroll
            for (int ct = 0; ct < 2; ++ct) {
                int ot = w*2 + ct;
                s16x8 b = *(const s16x8*)&Wx2pk[((ot*8 + ks)*64 + lane)*8];
                acc[0][ct] = MFMA(a0, b, acc[0][ct]);
                acc[1][ct] = MFMA(a1, b, acc[1][ct]);
            }
        }
        #pragma unroll
        for (int mw = 0; mw < 2; ++mw)
        #pragma unroll
        for (int ct = 0; ct < 2; ++ct) {
            int o = w*32 + ct*16 + cl;
            float bias = bx2[o];
            size_t rb = (size_t)(base + mw*16 + lg*4)*256 + o;
            unsigned u0 = cvtpk(acc[mw][ct][0]+bias, acc[mw][ct][1]+bias);
            unsigned u1 = cvtpk(acc[mw][ct][2]+bias, acc[mw][ct][3]+bias);
            X3b[rb      ] = (unsigned short)u0;
            X3b[rb + 256] = (unsigned short)(u0 >> 16);
            X3b[rb + 512] = (unsigned short)u1;
            X3b[rb + 768] = (unsigned short)(u1 >> 16);
        }
    }
}

// ---------------- kB v9: 2 waves/point, c-range split, barrier-free ----------------
// 512 thr = 8 waves, 4 points/block. Wave (u,hf): point p = blk*4+u.
//  hf=0: FC1+FC2 -> fcT[c<64][rw..], then ct 0..3 (reads only c<64 = own writes)
//  hf=1: fts stage -> fcT[c>=64][rw..], then ct 4..7 (own writes)
// No __syncthreads: every wave reads only LDS it wrote (in-order DS pipe).
#define SF 72
__global__ __launch_bounds__(512) void kB_mfma(
    const float* __restrict__ rep, const float* __restrict__ pts,
    const float* __restrict__ fts, const float* __restrict__ W1p,
    const unsigned short* __restrict__ Wpk, const float* __restrict__ bf2,
    const unsigned short* __restrict__ Wtb, const float* __restrict__ bdw,
    const unsigned short* __restrict__ X3b, unsigned short* __restrict__ dwPk)
{
    const unsigned short* Wf2pk = Wpk + 147456;
    __shared__ __align__(16) unsigned short fcT[128*SF];  // [c][row0..63], 18432 B
    const int tid = threadIdx.x;
    const int w = tid >> 6, lane = tid & 63, cl = lane & 15, lg = lane >> 4;
    const int u = w >> 1, hf = w & 1;
    const int p = blockIdx.x*4 + u;
    const int rw = u*16;

    // X A-frag (K 16->32 zero-pad) — both halves need it; issue first
    s16x8 xa = {0,0,0,0,0,0,0,0};
    if (lg < 2) xa = *(const s16x8*)&X3b[(size_t)p*256 + cl*16 + lg*8];

    f32x4 z = {0.f,0.f,0.f,0.f};

    if (hf == 0) {
        // ---- lift half: FC1 (regs) + FC2 (swapped MFMA) -> fcT[c<64] ----
        const int row = p*16 + cl;
        float x0 = pts[(size_t)row*3+0] - rep[p*3+0];
        float x1 = pts[(size_t)row*3+1] - rep[p*3+1];
        float x2 = pts[(size_t)row*3+2] - rep[p*3+2];
        s16x8 hb[2];
        #pragma unroll
        for (int ks = 0; ks < 2; ++ks) {
            uint4 hu;
            #pragma unroll
            for (int e2 = 0; e2 < 4; ++e2) {
                int f0 = ks*32 + lg*8 + e2*2;
                float4 wa = *(const float4*)&W1p[f0*4];
                float4 wb = *(const float4*)&W1p[(f0+1)*4];
                float h0 = fmaxf(wa.w + wa.x*x0 + wa.y*x1 + wa.z*x2, 0.f);
                float h1 = fmaxf(wb.w + wb.x*x0 + wb.y*x1 + wb.z*x2, 0.f);
                ((unsigned*)&hu)[e2] = cvtpk(h0, h1);
            }
            hb[ks] = __builtin_bit_cast(s16x8, hu);
        }
        f32x4 acc2[4] = {z,z,z,z};
        #pragma unroll
        for (int ks = 0; ks < 2; ++ks) {
            #pragma unroll
            for (int gt = 0; gt < 4; ++gt) {
                s16x8 a = *(const s16x8*)&Wf2pk[((gt*2 + ks)*64 + lane)*8];
                acc2[gt] = MFMA(a, hb[ks], acc2[gt]);
            }
        }
        #pragma unroll
        for (int gt = 0; gt < 4; ++gt) {
            int g0 = gt*16 + lg*4;
            unsigned u0 = cvtpk(fmaxf(acc2[gt][0]+bf2[g0+0],0.f),
                                fmaxf(acc2[gt][1]+bf2[g0+1],0.f));
            unsigned u1 = cvtpk(fmaxf(acc2[gt][2]+bf2[g0+2],0.f),
                                fmaxf(acc2[gt][3]+bf2[g0+3],0.f));
            int rb = g0*SF + rw + cl;
            fcT[rb       ] = (unsigned short)u0;
            fcT[rb +   SF] = (unsigned short)(u0 >> 16);
            fcT[rb + 2*SF] = (unsigned short)u1;
            fcT[rb + 3*SF] = (unsigned short)(u1 >> 16);
        }
    } else {
        // ---- fts half: transposed stage -> fcT[c>=64] ----
        const int frow = lane >> 2, fch = lane & 3;
        float4 fv[4];
        #pragma unroll
        for (int it = 0; it < 4; ++it)
            fv[it] = *(const float4*)&fts[((size_t)p*16 + frow)*64 + fch*4 + it*16];
        #pragma unroll
        for (int it = 0; it < 4; ++it) {
            int c0 = fch*4 + it*16;
            unsigned u0 = cvtpk(fv[it].x, fv[it].y);
            unsigned u1 = cvtpk(fv[it].z, fv[it].w);
            int rb = (64 + c0)*SF + rw + frow;
            fcT[rb       ] = (unsigned short)u0;
            fcT[rb +   SF] = (unsigned short)(u0 >> 16);
            fcT[rb + 2*SF] = (unsigned short)u1;
            fcT[rb + 3*SF] = (unsigned short)(u1 >> 16);
        }
    }

    // ---- own-half fts_X + depthwise (reads only this wave's fcT region) ----
    const int ctb = hf*4;
    #pragma unroll
    for (int ci = 0; ci < 4; ++ci) {
        int ct = ctb + ci;
        int c = ct*16 + cl;
        s16x8 b = *(const s16x8*)&fcT[c*SF + rw + (lg & 1)*8];
        f32x4 fx = MFMA(xa, b, z);

        float4 b4 = *(const float4*)&bdw[c*4];
        float om[4];
        #pragma unroll
        for (int m = 0; m < 4; ++m) {
            ushort4 wu = *(const ushort4*)&Wtb[m*2048 + c*16 + lg*4];
            float s = fx[0]*b2f(wu.x) + fx[1]*b2f(wu.y)
                    + fx[2]*b2f(wu.z) + fx[3]*b2f(wu.w);
            s += __shfl_xor(s, 16);
            s += __shfl_xor(s, 32);
            om[m] = s + ((const float*)&b4)[m];
        }
        if (lg == 0) {
            unsigned u0 = cvtpk(om[0], om[1]);
            unsigned u1 = cvtpk(om[2], om[3]);
            uint2 pk; pk.x = u0; pk.y = u1;
            size_t a = ((((size_t)(p >> 4)*16 + ct*2 + (cl >> 3))*64
                        + ((cl >> 1) & 3)*16 + (p & 15))*8 + (cl & 1)*4);
            *(uint2*)&dwPk[a] = pk;
        }
    }
}

// ---------------- kC: pointwise MFMA GEMM (packed A) + BN stats, y bf16 ----------------
__global__ __launch_bounds__(256) void kC_mfma(
    const unsigned short* __restrict__ dwPk, const unsigned short* __restrict__ Wpk,
    const float* __restrict__ bpw, unsigned short* __restrict__ yb,
    float* __restrict__ accS, float* __restrict__ accS2)
{
    const unsigned short* Wpwpk = Wpk + 151552;
    const int tid = threadIdx.x;
    const int w = tid >> 6, lane = tid & 63, cl = lane & 15, lg = lane >> 4;
    const int mt0 = blockIdx.x*2;              // two 16-point m-tiles per block
    const int nh = w & 3;                      // wave = N-quarter (2 ct)
    f32x4 z = {0.f,0.f,0.f,0.f};
    f32x4 acc[2][2] = {{z,z},{z,z}};           // [mt][ct]
    for (int ks = 0; ks < 16; ++ks) {
        s16x8 a0 = *(const s16x8*)&dwPk[(((size_t)mt0*16 + ks)*64 + lane)*8];
        s16x8 a1 = *(const s16x8*)&dwPk[(((size_t)(mt0+1)*16 + ks)*64 + lane)*8];
        #pragma unroll
        for (int ct = 0; ct < 2; ++ct) {
            int ot = nh*2 + ct;
            s16x8 b = *(const s16x8*)&Wpwpk[((ot*16 + ks)*64 + lane)*8];
            acc[0][ct] = MFMA(a0, b, acc[0][ct]);
            acc[1][ct] = MFMA(a1, b, acc[1][ct]);
        }
    }
    #pragma unroll
    for (int mt = 0; mt < 2; ++mt)
    #pragma unroll
    for (int ct = 0; ct < 2; ++ct) {
        int o = nh*32 + ct*16 + cl;
        float bias = bpw[o];
        float s1 = 0.f, s2 = 0.f;
        #pragma unroll
        for (int r = 0; r < 4; ++r) {
            float v = acc[mt][ct][r] + bias;
            yb[(size_t)((mt0+mt)*16 + lg*4 + r)*128 + o] = f2b(v);
            s1 += v; s2 += v*v;
        }
        s1 += __shfl_xor(s1, 16); s2 += __shfl_xor(s2, 16);
        s1 += __shfl_xor(s1, 32); s2 += __shfl_xor(s2, 32);
        if (lg == 0) {
            atomicAdd(accS + o, s1);
            atomicAdd(accS2 + o, s2);
        }
    }
}

// ---------------- kE: BN finalize (inline) + normalize + relu, bf16 y in ----------------
__global__ __launch_bounds__(256) void kE_final(
    const unsigned short* __restrict__ yb, const float* __restrict__ accS,
    const float* __restrict__ accS2, const float* __restrict__ gamma,
    const float* __restrict__ beta, float* __restrict__ out)
{
    __shared__ float stl[256];
    const int tid = threadIdx.x;
    if (tid < 128) {
        float mean = accS[tid] * (1.f/NPTS);
        float var  = accS2[tid] * (1.f/NPTS) - mean*mean;
        float rstd = rsqrtf(var + 1e-5f);
        float sc = gamma[tid] * rstd;
        stl[tid] = sc;
        stl[128 + tid] = beta[tid] - mean*sc;
    }
    __syncthreads();
    const int idx = blockIdx.x*256 + tid;
    ushort4 u = *(const ushort4*)&yb[(size_t)idx*4];
    int o0 = (idx & 31) << 2;
    float4 sc = *(const float4*)&stl[o0];
    float4 sh = *(const float4*)&stl[128 + o0];
    float4 r;
    r.x = fmaxf(b2f(u.x)*sc.x + sh.x, 0.f);
    r.y = fmaxf(b2f(u.y)*sc.y + sh.y, 0.f);
    r.z = fmaxf(b2f(u.z)*sc.z + sh.z, 0.f);
    r.w = fmaxf(b2f(u.w)*sc.w + sh.w, 0.f);
    ((float4*)out)[idx] = r;
}

extern "C" void kernel_launch(void* const* d_in, const int* in_sizes, int n_in,
                              void* d_out, int out_size, void* d_ws, size_t ws_size,
                              hipStream_t stream) {
    const float* rep  = (const float*)d_in[0];
    const float* pts  = (const float*)d_in[1];
    const float* fts  = (const float*)d_in[2];
    const float* Wf1  = (const float*)d_in[3];
    const float* bf1  = (const float*)d_in[4];
    const float* Wf2  = (const float*)d_in[5];
    const float* bf2  = (const float*)d_in[6];
    const float* Wxc  = (const float*)d_in[7];
    const float* bxc  = (const float*)d_in[8];
    const float* Wx1  = (const float*)d_in[9];
    const float* bx1  = (const float*)d_in[10];
    const float* Wx2  = (const float*)d_in[11];
    const float* bx2  = (const float*)d_in[12];
    const float* Wdw  = (const float*)d_in[13];
    const float* bdw  = (const float*)d_in[14];
    const float* Wpw  = (const float*)d_in[15];
    const float* bpw  = (const float*)d_in[16];
    const float* gam  = (const float*)d_in[17];
    const float* bet  = (const float*)d_in[18];

    unsigned short* X3b  = (unsigned short*)d_ws;                // 16384*256 bf16
    unsigned short* dwPk = X3b + (size_t)NPTS*256;               // 16384*512 bf16
    unsigned short* yb   = dwPk + (size_t)NPTS*512;              // 16384*128 bf16
    float* acc = (float*)(yb + (size_t)NPTS*128);                // 256 (accS|accS2)
    unsigned short* Wpk = (unsigned short*)(acc + 256);          // 217088 bf16
    float* W1p = (float*)(Wpk + 217088);                         // 256 f32
    unsigned short* Wtb = (unsigned short*)(W1p + 256);          // 8192 bf16

    kW_cvt<<<882, 256, 0, stream>>>(Wxc, Wx1, Wx2, Wf2, Wpw, Wf1, bf1, Wdw,
                                    Wpk, W1p, Wtb, acc);
    kA_mfma<<<NPTS/32, 512, 0, stream>>>(rep, pts, Wpk, bxc, bx1, bx2, X3b);
    kB_mfma<<<NPTS/4, 512, 0, stream>>>(rep, pts, fts, W1p, Wpk, bf2, Wtb, bdw, X3b, dwPk);
    kC_mfma<<<NPTS/32, 256, 0, stream>>>(dwPk, Wpk, bpw, yb, acc, acc + 128);
    kE_final<<<(NPTS*128/4)/256, 256, 0, stream>>>(yb, acc, acc + 128, gam, bet, (float*)d_out);
}